// Round 9
// baseline (252.112 us; speedup 1.0000x reference)
//
#include <hip/hip_runtime.h>
#include <hip/hip_bf16.h>

typedef __attribute__((ext_vector_type(8))) short short8;
typedef __attribute__((ext_vector_type(4))) short short4v;
typedef __attribute__((ext_vector_type(4))) float f32x4;

__device__ __forceinline__ unsigned short f2bf(float f) {
    __hip_bfloat16 h = __float2bfloat16(f);
    unsigned short u;
    __builtin_memcpy(&u, &h, 2);
    return u;
}
__device__ __forceinline__ short4v pack4bf(float a, float b, float c, float d) {
    union { unsigned u[2]; short4v s; } r;
    r.u[0] = ((unsigned)f2bf(b) << 16) | f2bf(a);
    r.u[1] = ((unsigned)f2bf(d) << 16) | f2bf(c);
    return r.s;
}

#define GLD16(gp, lp) __builtin_amdgcn_global_load_lds( \
    (const __attribute__((address_space(1))) void*)(gp), \
    (__attribute__((address_space(3))) void*)(lp), 16, 0, 0)

// ---------------------------------------------------------------------------
// prep: fused f32->bf16 convert of q,k,v (blocks 0..6143) + weight transpose
// (blocks 6144..7167).
// ---------------------------------------------------------------------------
__global__ __launch_bounds__(256) void prep(
    const float* __restrict__ q, const float* __restrict__ k, const float* __restrict__ v,
    unsigned short* __restrict__ qb, unsigned short* __restrict__ kb, unsigned short* __restrict__ vb,
    const float* __restrict__ W0, const float* __restrict__ W1,
    const float* __restrict__ W2, const float* __restrict__ W3,
    unsigned short* __restrict__ T0, unsigned short* __restrict__ T1,
    unsigned short* __restrict__ T2, unsigned short* __restrict__ T3)
{
    __shared__ unsigned short Ts[64 * 72];
    int bx = blockIdx.x;
    if (bx < 6144) {
        const float* src; unsigned short* dst;
        switch (bx >> 11) { case 0: src = q; dst = qb; break;
                            case 1: src = k; dst = kb; break;
                            default: src = v; dst = vb; break; }
        size_t i = ((size_t)(bx & 2047) * 256 + threadIdx.x) * 8;
        float4 x0 = *(const float4*)&src[i];
        float4 x1 = *(const float4*)&src[i + 4];
        union { unsigned short s[8]; uint4 u; } p;
        p.s[0] = f2bf(x0.x); p.s[1] = f2bf(x0.y); p.s[2] = f2bf(x0.z); p.s[3] = f2bf(x0.w);
        p.s[4] = f2bf(x1.x); p.s[5] = f2bf(x1.y); p.s[6] = f2bf(x1.z); p.s[7] = f2bf(x1.w);
        *(uint4*)&dst[i] = p.u;
        return;
    }
    int w = bx - 6144;
    int z = w >> 8, rem = w & 255;
    int kx = rem >> 4, ny = rem & 15;
    const float* W;
    unsigned short* T;
    switch (z) {
        case 0: W = W0; T = T0; break;
        case 1: W = W1; T = T1; break;
        case 2: W = W2; T = T2; break;
        default: W = W3; T = T3; break;
    }
    int tid = threadIdx.x;
    int c = tid & 7, r = tid >> 3;
    int k0 = kx * 64, n0 = ny * 64;
    for (int i = 0; i < 64; i += 32) {
        const float* src = &W[(size_t)(k0 + r + i) * 1024 + n0 + c * 8];
        float4 x0 = *(const float4*)src;
        float4 x1 = *(const float4*)(src + 4);
        unsigned short* d = &Ts[(r + i) * 72 + c * 8];
        d[0] = f2bf(x0.x); d[1] = f2bf(x0.y); d[2] = f2bf(x0.z); d[3] = f2bf(x0.w);
        d[4] = f2bf(x1.x); d[5] = f2bf(x1.y); d[6] = f2bf(x1.z); d[7] = f2bf(x1.w);
    }
    __syncthreads();
    for (int i = 0; i < 64; i += 32) {
        union { unsigned short s[8]; uint4 v; } u;
        for (int j = 0; j < 8; j++) u.s[j] = Ts[(c * 8 + j) * 72 + (r + i)];
        *(uint4*)&T[(size_t)(n0 + r + i) * 1024 + k0 + c * 8] = u.v;
    }
}

// ---------------------------------------------------------------------------
// GEMM core v4: 128x128, BK=32, single-buffered swizzled global_load_lds.
// Modes 0/1 compute TRANSPOSED (mfma(b,a) -> D[n][m]): lane holds 4
// consecutive output cols (n=quad*4+r) of one row (m=lm) -> packed stores
// (mode 0: float4; mode 1: ushort4) instead of scalar scatter. Mode 2 keeps
// the original orientation (its [bh][d][t] layout packs rows).
// ---------------------------------------------------------------------------
__device__ __forceinline__ void gemm_core(
    const unsigned short* __restrict__ A, const unsigned short* __restrict__ BT,
    const float* __restrict__ bias, void* __restrict__ outv,
    int mode, float scale)
{
    const int K = 1024;
    __shared__ unsigned short As[128 * 32];
    __shared__ unsigned short Bs[128 * 32];
    int tid = threadIdx.x;
    int m0 = blockIdx.x * 128, n0 = blockIdx.y * 128;
    int lane = tid & 63, wave = tid >> 6;
    int lm = lane & 15, quad = lane >> 4;
    int wm = (wave >> 1) * 64, wn = (wave & 1) * 64;

    int lrow = lane >> 2;
    int scol = ((lane & 3) ^ ((lane >> 3) & 3)) * 8;
    const unsigned short* Ag = A + (size_t)(m0 + wave * 32 + lrow) * K + scol;
    const unsigned short* Bg = BT + (size_t)(n0 + wave * 32 + lrow) * K + scol;
    unsigned short* AsW0 = &As[(wave * 32) * 32];
    unsigned short* AsW1 = &As[(wave * 32 + 16) * 32];
    unsigned short* BsW0 = &Bs[(wave * 32) * 32];
    unsigned short* BsW1 = &Bs[(wave * 32 + 16) * 32];

    int rpos = (quad ^ ((lm >> 1) & 3)) * 8;

    f32x4 acc[4][4];
    for (int i = 0; i < 4; i++)
        for (int j = 0; j < 4; j++)
            for (int r = 0; r < 4; r++) acc[i][j][r] = 0.0f;

    for (int kb = 0; kb < K; kb += 32) {
        GLD16(Ag, AsW0);
        GLD16(Ag + 16 * K, AsW1);
        GLD16(Bg, BsW0);
        GLD16(Bg + 16 * K, BsW1);
        Ag += 32; Bg += 32;
        __syncthreads();
        short8 a[4], b[4];
        for (int i = 0; i < 4; i++)
            a[i] = *(const short8*)&As[(wm + i * 16 + lm) * 32 + rpos];
        for (int j = 0; j < 4; j++)
            b[j] = *(const short8*)&Bs[(wn + j * 16 + lm) * 32 + rpos];
        if (mode == 2) {
            for (int i = 0; i < 4; i++)
                for (int j = 0; j < 4; j++)
                    acc[i][j] = __builtin_amdgcn_mfma_f32_16x16x32_bf16(a[i], b[j], acc[i][j], 0, 0, 0);
        } else {
            for (int i = 0; i < 4; i++)
                for (int j = 0; j < 4; j++)
                    acc[i][j] = __builtin_amdgcn_mfma_f32_16x16x32_bf16(b[j], a[i], acc[i][j], 0, 0, 0);
        }
        __syncthreads();
    }

    if (mode == 0) {
        float* out32 = (float*)outv;
        for (int j = 0; j < 4; j++) {
            int cbase = n0 + wn + j * 16 + quad * 4;
            float4 b4 = *(const float4*)&bias[cbase];
            for (int i = 0; i < 4; i++) {
                int row = m0 + wm + i * 16 + lm;
                float4 st;
                st.x = (acc[i][j][0] + b4.x) * scale;
                st.y = (acc[i][j][1] + b4.y) * scale;
                st.z = (acc[i][j][2] + b4.z) * scale;
                st.w = (acc[i][j][3] + b4.w) * scale;
                *(float4*)&out32[(size_t)row * 1024 + cbase] = st;
            }
        }
    } else if (mode == 1) {
        unsigned short* out16 = (unsigned short*)outv;
        for (int j = 0; j < 4; j++) {
            int cbase = n0 + wn + j * 16 + quad * 4;   // d index, multiple of 4
            float4 b4 = *(const float4*)&bias[cbase];
            int h = cbase >> 6, d0 = cbase & 63;
            for (int i = 0; i < 4; i++) {
                int rowm = m0 + wm + i * 16 + lm;
                int bb = rowm >> 11, t = rowm & 2047;
                ushort4 pk;
                pk.x = f2bf((acc[i][j][0] + b4.x) * scale);
                pk.y = f2bf((acc[i][j][1] + b4.y) * scale);
                pk.z = f2bf((acc[i][j][2] + b4.z) * scale);
                pk.w = f2bf((acc[i][j][3] + b4.w) * scale);
                *(ushort4*)&out16[(((size_t)(bb * 16 + h)) * 2048 + t) * 64 + d0] = pk;
            }
        }
    } else {
        unsigned short* out16 = (unsigned short*)outv;
        for (int j = 0; j < 4; j++) {
            int col = n0 + wn + j * 16 + lm;
            float bv = bias[col];
            for (int i = 0; i < 4; i++) {
                int rowb = m0 + wm + i * 16 + quad * 4;
                int h = col >> 6, d = col & 63;
                int bb = rowb >> 11, t = rowb & 2047;   // t is 4-aligned
                ushort4 pk;
                pk.x = f2bf((acc[i][j][0] + bv) * scale);
                pk.y = f2bf((acc[i][j][1] + bv) * scale);
                pk.z = f2bf((acc[i][j][2] + bv) * scale);
                pk.w = f2bf((acc[i][j][3] + bv) * scale);
                *(ushort4*)&out16[(((size_t)(bb * 16 + h)) * 64 + d) * 2048 + t] = pk;
            }
        }
    }
}

// Fused QKV projections: blockIdx.z selects {q,k,v}; 768 blocks = 3/CU.
__global__ __launch_bounds__(256) void qkv_gemm(
    const unsigned short* __restrict__ qbf, const unsigned short* __restrict__ kbf,
    const unsigned short* __restrict__ vbf,
    const unsigned short* __restrict__ WqT, const unsigned short* __restrict__ WkT,
    const unsigned short* __restrict__ WvT,
    const float* __restrict__ bq, const float* __restrict__ bk, const float* __restrict__ bv,
    unsigned short* __restrict__ Qh, unsigned short* __restrict__ Kh,
    unsigned short* __restrict__ VhT)
{
    switch (blockIdx.z) {
        case 0:  gemm_core(qbf, WqT, bq, Qh,  1, 0.18033688011f); break; // log2e/8
        case 1:  gemm_core(kbf, WkT, bk, Kh,  1, 1.0f);           break;
        default: gemm_core(vbf, WvT, bv, VhT, 2, 1.0f);           break;
    }
}

__global__ __launch_bounds__(256) void out_gemm(
    const unsigned short* __restrict__ X, const unsigned short* __restrict__ WoT,
    const float* __restrict__ bo, float* __restrict__ out)
{
    gemm_core(X, WoT, bo, out, 0, 1.0f);
}

// ---------------------------------------------------------------------------
// Flash attention v6: TQ=128 (512 blocks; each wave owns 32 q-rows as two
// 16-row groups). Staged K-frags (b128) and V-frags (b64) are loaded ONCE
// and reused for both q-groups -> half the LDS reads / staging / barriers
// per FLOP vs v5. P stays in registers (transposed QK^T: mfma(K,Q) ->
// D[key][q]; PV via 16x16x16bf16_1k). exp2 with log2e folded into Q proj.
// ---------------------------------------------------------------------------
__global__ __launch_bounds__(256) void attn_kernel(
    const unsigned short* __restrict__ Qh, const unsigned short* __restrict__ Kh,
    const unsigned short* __restrict__ VhT, unsigned short* __restrict__ X)
{
    __shared__ unsigned short Ks[2][64 * 64];
    __shared__ unsigned short Vt[2][64 * 64];

    int tid = threadIdx.x;
    int qb = blockIdx.x & 15, bh = blockIdx.x >> 4;
    int b = bh >> 4, h = bh & 15;
    int lane = tid & 63, wave = tid >> 6;
    int lm = lane & 15, quad = lane >> 4;

    const unsigned short* Kbase = Kh + (size_t)bh * 2048 * 64;
    const unsigned short* Vbase = VhT + (size_t)bh * 64 * 2048;

    int srow = wave * 8 + (lane >> 3);
    int schk = ((lane & 7) ^ ((lane >> 3) & 7)) * 8;
    int swz  = lm & 7;
    int c0 = (quad ^ swz) * 8;
    int c1 = ((quad + 4) ^ swz) * 8;

    // two q-groups per wave: rows qb*128 + wave*32 + {0,16} + lm
    int qrow = qb * 128 + wave * 32 + lm;
    const unsigned short* qptr0 = Qh + ((size_t)bh * 2048 + qrow) * 64;
    const unsigned short* qptr1 = qptr0 + 16 * 64;
    short8 qf[2][2];
    qf[0][0] = *(const short8*)&qptr0[quad * 8];
    qf[0][1] = *(const short8*)&qptr0[32 + quad * 8];
    qf[1][0] = *(const short8*)&qptr1[quad * 8];
    qf[1][1] = *(const short8*)&qptr1[32 + quad * 8];

    f32x4 o[2][4];
    for (int qs = 0; qs < 2; qs++)
        for (int n = 0; n < 4; n++)
            for (int r = 0; r < 4; r++) o[qs][n][r] = 0.0f;
    float lsum[2] = {0.0f, 0.0f};

    GLD16(&Kbase[(size_t)srow * 64 + schk],          &Ks[0][(wave * 8) * 64]);
    GLD16(&Kbase[(size_t)(32 + srow) * 64 + schk],   &Ks[0][(32 + wave * 8) * 64]);
    GLD16(&Vbase[(size_t)srow * 2048 + schk],        &Vt[0][(wave * 8) * 64]);
    GLD16(&Vbase[(size_t)(32 + srow) * 2048 + schk], &Vt[0][(32 + wave * 8) * 64]);
    __syncthreads();

    for (int kt = 0; kt < 32; kt++) {
        int cur = kt & 1;
        if (kt < 31) {
            int k1 = (kt + 1) * 64;
            int nxt = cur ^ 1;
            GLD16(&Kbase[(size_t)(k1 + srow) * 64 + schk],        &Ks[nxt][(wave * 8) * 64]);
            GLD16(&Kbase[(size_t)(k1 + 32 + srow) * 64 + schk],   &Ks[nxt][(32 + wave * 8) * 64]);
            GLD16(&Vbase[(size_t)srow * 2048 + k1 + schk],        &Vt[nxt][(wave * 8) * 64]);
            GLD16(&Vbase[(size_t)(32 + srow) * 2048 + k1 + schk], &Vt[nxt][(32 + wave * 8) * 64]);
        }

        // S^T per 16-key tile t; K-frags shared across both q-groups
        short4v pa[2][4];
        for (int t = 0; t < 4; t++) {
            short8 ka0 = *(const short8*)&Ks[cur][(t * 16 + lm) * 64 + c0];
            short8 ka1 = *(const short8*)&Ks[cur][(t * 16 + lm) * 64 + c1];
            for (int qs = 0; qs < 2; qs++) {
                f32x4 z;
                z[0] = z[1] = z[2] = z[3] = 0.0f;
                z = __builtin_amdgcn_mfma_f32_16x16x32_bf16(ka0, qf[qs][0], z, 0, 0, 0);
                z = __builtin_amdgcn_mfma_f32_16x16x32_bf16(ka1, qf[qs][1], z, 0, 0, 0);
                float p0 = __builtin_amdgcn_exp2f(z[0]);
                float p1 = __builtin_amdgcn_exp2f(z[1]);
                float p2 = __builtin_amdgcn_exp2f(z[2]);
                float p3 = __builtin_amdgcn_exp2f(z[3]);
                lsum[qs] += (p0 + p1) + (p2 + p3);
                pa[qs][t] = pack4bf(p0, p1, p2, p3);
            }
        }

        // O += P V; V-frags shared across both q-groups
        int wo = (quad & 1) * 4;
        for (int n = 0; n < 4; n++) {
            int rbase = (n * 16 + lm) * 64;
            for (int t = 0; t < 4; t++) {
                int chunk = t * 2 + (quad >> 1);
                short4v vb = *(const short4v*)&Vt[cur][rbase + ((chunk ^ swz) * 8) + wo];
                o[0][n] = __builtin_amdgcn_mfma_f32_16x16x16bf16_1k(pa[0][t], vb, o[0][n], 0, 0, 0);
                o[1][n] = __builtin_amdgcn_mfma_f32_16x16x16bf16_1k(pa[1][t], vb, o[1][n], 0, 0, 0);
            }
        }
        __syncthreads();
    }

    for (int qs = 0; qs < 2; qs++) {
        float l = lsum[qs];
        l += __shfl_xor(l, 16);
        l += __shfl_xor(l, 32);
        float inv = 1.0f / l;
        for (int r = 0; r < 4; r++) {
            float invr = __shfl(inv, (lane & 48) | (quad * 4 + r));
            int row = qb * 128 + wave * 32 + qs * 16 + quad * 4 + r;
            for (int n = 0; n < 4; n++)
                X[((size_t)b * 2048 + row) * 1024 + h * 64 + n * 16 + lm] = f2bf(o[qs][n][r] * invr);
        }
    }
}

// ---------------------------------------------------------------------------
extern "C" void kernel_launch(void* const* d_in, const int* in_sizes, int n_in,
                              void* d_out, int out_size, void* d_ws, size_t ws_size,
                              hipStream_t stream)
{
    const float* q  = (const float*)d_in[0];
    const float* k  = (const float*)d_in[1];
    const float* v  = (const float*)d_in[2];
    const float* Wq = (const float*)d_in[3];
    const float* bq = (const float*)d_in[4];
    const float* Wk = (const float*)d_in[5];
    const float* bk = (const float*)d_in[6];
    const float* Wv = (const float*)d_in[7];
    const float* bv = (const float*)d_in[8];
    const float* Wo = (const float*)d_in[9];
    const float* bo = (const float*)d_in[10];

    // 40 MB ws layout, sequential aliasing:
    //  0- 4M: WqT,WkT,WvT,WoT (1M elems each)
    //  4- 8M: qbf -> Kh | 8-12M: kbf -> VhT | 12-16M: vbf -> X | 16-20M: Qh
    unsigned short* ws  = (unsigned short*)d_ws;
    const unsigned int M1 = 1u << 20;
    unsigned short* WqT = ws;
    unsigned short* WkT = ws + M1;
    unsigned short* WvT = ws + 2 * M1;
    unsigned short* WoT = ws + 3 * M1;
    unsigned short* qbf = ws + 4 * M1;
    unsigned short* kbf = ws + 8 * M1;
    unsigned short* vbf = ws + 12 * M1;
    unsigned short* Qh  = ws + 16 * M1;
    unsigned short* Kh  = ws + 4 * M1;    // over dead qbf
    unsigned short* VhT = ws + 8 * M1;    // over dead kbf
    unsigned short* X   = ws + 12 * M1;   // over dead vbf

    prep<<<dim3(7168), 256, 0, stream>>>(q, k, v, qbf, kbf, vbf,
                                         Wq, Wk, Wv, Wo, WqT, WkT, WvT, WoT);
    qkv_gemm<<<dim3(32, 8, 3), 256, 0, stream>>>(qbf, kbf, vbf, WqT, WkT, WvT,
                                                 bq, bk, bv, Qh, Kh, VhT);
    attn_kernel<<<dim3(512), 256, 0, stream>>>(Qh, Kh, VhT, X);
    out_gemm<<<dim3(32, 8), 256, 0, stream>>>(X, WoT, bo, (float*)d_out);
}